// Round 8
// baseline (763.637 us; speedup 1.0000x reference)
//
#include <hip/hip_runtime.h>
#include <math.h>

// ComponentPointPredictor: ragged autoregressive point prediction.
// Round 8: round-4 verified geometry (IT=4, NT=512, half-split fp64 matvec,
// persistent + atomic refill queue) with occupancy raised to 3 blocks/CU
// (24 waves/CU = 6 waves/SIMD): s_x stored fp32 (exact: x is fp32 data),
// LDS 28.4 KB/block, NBLK=768, NSLOT=3072 (1024 refills for balance),
// pred_W cached in 32 regs/lane. Round 7 lesson: 1 block/CU exposes every
// barrier + Phase-C transcendental chain (VALUBusy 17%); cross-block
// overlap is what made round 4 work. Rounds 5/6 lesson: weight files
// >~100 regs spill (backend targets 4 waves/EU).
// Numerics identical to verified rounds 2-7 (absmax 0.0234375): fp64
// matvec accumulation, fp32 temp-50000 softmax -> soft-argmax -> floor
// chain op-for-op like the reference.

#define CTX     256
#define INIT    32
#define HID     256
#define WIN     63
#define MSTEPS  224            // CTX - INIT
#define OUTROW  (MSTEPS + CTX) // 480
#define IT      4
#define NT      512
#define KH      112            // half0: in_W(32) + hid_W k<112; half1: k in [112,256)
#define NBLK    768            // 3 blocks/CU
#define NSLOT   (NBLK * IT)    // 3072 -> 1024 refills

__global__ void init_counter_kernel(int* cnt, int v) { *cnt = v; }

__global__ void __launch_bounds__(NT)
cpp_kernel(const float* __restrict__ x,
           const float* __restrict__ hid_W,
           const float* __restrict__ hid_b,
           const float* __restrict__ in_W,
           const float* __restrict__ in_b,
           const float* __restrict__ pred_W,
           const float* __restrict__ pred_b,
           float* __restrict__ out,
           int* __restrict__ cnt, int B)
{
    __shared__ float  s_x[IT][CTX];       // 4 KB  fp32 x rows (exact; cast at use)
    __shared__ double s_hid[IT][HID];     // 8 KB  fp64 hidden carry
    __shared__ double s_scr[IT][8][64];   // 16 KB B partials; first 8 KB = A-reduce
    __shared__ int    s_lastl[IT];
    __shared__ int    s_act[IT];

    const int tid  = threadIdx.x;
    const int lane = tid & 63;
    const int q    = tid >> 6;           // wave 0..7; waves 0..3 own slots
    const int j    = tid & (HID - 1);    // hidden unit
    const int half = tid >> 8;           // k-split half 0/1

    // pred_W rows [32q, 32q+32) cached in registers (col = lane)
    float pwreg[32];
    const int kb = q * 32;
    #pragma unroll
    for (int kk = 0; kk < 32; ++kk)
        pwreg[kk] = (lane < WIN) ? pred_W[(kb + kk) * WIN + lane] : 0.0f;
    const float  pbias = (lane < WIN) ? pred_b[lane] : 0.0f;
    const double bias  = (half == 0) ? ((double)hid_b[j] + (double)in_b[j]) : 0.0;
    double* const red = &s_scr[0][0][0]; // [IT*HID] view for A-reduce

    // wave-local slot state (waves q < IT own slot q)
    int   myitem = -1;
    float mylast = (float)INIT;
    int   sc = 0;

    // ---- initial static claim: slot q <- item blockIdx*IT + q (< 3072 < B) ----
    if (q < IT) {
        const int item = blockIdx.x * IT + q;
        myitem = item;
        float* orow = out + (size_t)item * OUTROW;
        for (int idx = lane; idx < OUTROW; idx += 64) orow[idx] = 0.0f;
        #pragma unroll
        for (int u = 0; u < 4; ++u)
            s_x[q][lane + 64 * u] = x[(size_t)item * CTX + lane + 64 * u];
        #pragma unroll
        for (int u = 0; u < 4; ++u) s_hid[q][lane + 64 * u] = 1.0;
        if (lane == 0) { s_lastl[q] = INIT; s_act[q] = 1; }
    }
    __syncthreads();

    for (int iter = 0; iter < (1 << 18); ++iter) {   // cap = hang-protect only
        int lastl[IT], act[IT];
        #pragma unroll
        for (int it = 0; it < IT; ++it) { lastl[it] = s_lastl[it]; act[it] = s_act[it]; }
        if (!(act[0] | act[1] | act[2] | act[3])) break;

        // ---- Phase A: partial pre-activation for unit j, k-half `half` ----
        double acc[IT];
        #pragma unroll
        for (int it = 0; it < IT; ++it) acc[it] = bias;

        if (half == 0) {
            int sb[IT];
            #pragma unroll
            for (int it = 0; it < IT; ++it) {
                int l = lastl[it]; if (l > CTX) l = CTX;
                sb[it] = l - INIT;                    // in [0, 224]
            }
            #pragma unroll 4
            for (int m = 0; m < INIT; ++m) {
                const double wv = (double)in_W[m * HID + j];
                #pragma unroll
                for (int it = 0; it < IT; ++it)
                    acc[it] = fma((double)s_x[it][sb[it] + m], wv, acc[it]);
            }
            #pragma unroll 8
            for (int g = 0; g < KH / 2; ++g) {        // k = 2g, 2g+1
                const double w0 = (double)hid_W[(size_t)(2 * g) * HID + j];
                const double w1 = (double)hid_W[(size_t)(2 * g + 1) * HID + j];
                #pragma unroll
                for (int it = 0; it < IT; ++it) {
                    const double2 h = *(const double2*)&s_hid[it][2 * g];
                    acc[it] = fma(h.x, w0, acc[it]);
                    acc[it] = fma(h.y, w1, acc[it]);
                }
            }
        } else {
            #pragma unroll 8
            for (int g = 0; g < 72; ++g) {            // k = KH + 2g, KH + 2g+1
                const double w0 = (double)hid_W[(size_t)(KH + 2 * g) * HID + j];
                const double w1 = (double)hid_W[(size_t)(KH + 2 * g + 1) * HID + j];
                #pragma unroll
                for (int it = 0; it < IT; ++it) {
                    const double2 h = *(const double2*)&s_hid[it][KH + 2 * g];
                    acc[it] = fma(h.x, w0, acc[it]);
                    acc[it] = fma(h.y, w1, acc[it]);
                }
            }
        }

        if (half == 1) {
            #pragma unroll
            for (int it = 0; it < IT; ++it) red[it * HID + j] = acc[it];
        }
        __syncthreads();   // (1) old-s_hid reads done; half1 partials visible

        if (half == 0) {
            #pragma unroll
            for (int it = 0; it < IT; ++it) {
                acc[it] += red[it * HID + j];
                if (act[it]) s_hid[it][j] = (double)tanhf((float)acc[it]);
            }
        }
        __syncthreads();   // (2) new hidden visible; red region free

        // ---- Phase B: w = hid @ pred_W, split-k: wave q covers rows [32q,32q+32) ----
        double pacc[IT] = {0.0, 0.0, 0.0, 0.0};
        #pragma unroll 8
        for (int kk = 0; kk < 32; ++kk) {
            const double wv = (double)pwreg[kk];
            #pragma unroll
            for (int it = 0; it < IT; ++it)
                pacc[it] = fma(s_hid[it][kb + kk], wv, pacc[it]);
        }
        #pragma unroll
        for (int it = 0; it < IT; ++it) s_scr[it][q][lane] = pacc[it];
        __syncthreads();   // (3) B partials visible

        // ---- Phase C: wave q owns slot q: fp32 softmax chain + refill ----
        if (q < IT && act[q]) {
            const int it = q;
            float t = -INFINITY;
            if (lane < WIN) {
                const double wv = s_scr[it][0][lane] + s_scr[it][1][lane]
                                + s_scr[it][2][lane] + s_scr[it][3][lane]
                                + s_scr[it][4][lane] + s_scr[it][5][lane]
                                + s_scr[it][6][lane] + s_scr[it][7][lane]
                                + (double)pbias;
                t = (float)wv * 50000.0f;            // fp32 temp scale like ref
            }
            float mx = t;
            #pragma unroll
            for (int off = 32; off > 0; off >>= 1)
                mx = fmaxf(mx, __shfl_xor(mx, off));
            const float e = (lane < WIN) ? expf(t - mx) : 0.0f;
            float S = e;
            #pragma unroll
            for (int off = 32; off > 0; off >>= 1)
                S += __shfl_xor(S, off);
            const float p = e / S;
            float D = p * (float)lane;
            #pragma unroll
            for (int off = 32; off > 0; off >>= 1)
                D += __shfl_xor(D, off);
            float cur = fminf(D + 1.0f, 63.0f);
            float se = fminf(cur + mylast, 256.0f);
            const int sel = (int)se;

            float* orow = out + (size_t)myitem * OUTROW;
            if (lane < WIN) {
                const int pos = lastl[it] + lane;
                if (pos < sel) {
                    const float msk = 1.0f / (1.0f + expf((float)lane - cur));
                    orow[MSTEPS + pos] = msk * s_x[it][pos];
                }
            }
            const bool done = (se >= 256.0f);        // final step's pt is dropped
            if (lane == 0 && !done) { orow[sc] = se; s_lastl[it] = sel; }
            sc++;
            mylast = se;

            if (done) {
                int nid = 0;
                if (lane == 0) nid = atomicAdd(cnt, 1);
                nid = __shfl(nid, 0);
                if (nid < B) {
                    myitem = nid; mylast = (float)INIT; sc = 0;
                    float* nrow = out + (size_t)nid * OUTROW;
                    for (int idx = lane; idx < OUTROW; idx += 64) nrow[idx] = 0.0f;
                    #pragma unroll
                    for (int u = 0; u < 4; ++u)
                        s_x[it][lane + 64 * u] = x[(size_t)nid * CTX + lane + 64 * u];
                    #pragma unroll
                    for (int u = 0; u < 4; ++u) s_hid[it][lane + 64 * u] = 1.0;
                    if (lane == 0) s_lastl[it] = INIT;   // s_act stays 1
                } else {
                    if (lane == 0) s_act[it] = 0;        // queue empty: slot dies
                }
            }
        }
        __syncthreads();   // (4) state/refill visible
    }
}

extern "C" void kernel_launch(void* const* d_in, const int* in_sizes, int n_in,
                              void* d_out, int out_size, void* d_ws, size_t ws_size,
                              hipStream_t stream) {
    const float* x      = (const float*)d_in[0];
    const float* hid_W  = (const float*)d_in[1];
    const float* hid_b  = (const float*)d_in[2];
    const float* in_W   = (const float*)d_in[3];
    const float* in_b   = (const float*)d_in[4];
    const float* pred_W = (const float*)d_in[5];
    const float* pred_b = (const float*)d_in[6];
    float* out = (float*)d_out;
    int*   cnt = (int*)d_ws;

    const int B = in_sizes[0] / CTX;     // 4096
    init_counter_kernel<<<1, 1, 0, stream>>>(cnt, NSLOT);
    cpp_kernel<<<NBLK, NT, 0, stream>>>(x, hid_W, hid_b, in_W, in_b,
                                        pred_W, pred_b, out, cnt, B);
}

// Round 9
// 332.113 us; speedup vs baseline: 2.2993x; 2.2993x over previous
//
#include <hip/hip_runtime.h>
#include <math.h>

// ComponentPointPredictor: ragged autoregressive point prediction.
// Round 9: simplified 3-barrier structure. NT=256, IT=4, NBLK=B/IT=1024
// (all items resident, 4 blocks/CU). Phase A: thread j computes the FULL
// 288-long dot for hidden unit j of all 4 items (no split-k -> no A-reduce
// barrier, no s_scr). Phase B+C: wave q owns item q end-to-end: lane l
// computes w[l] directly (256 MAC, pred_W coalesced), softmax wave-local.
// All 4 waves busy in every phase; 3 barriers/step (was 4).
// Lessons kept: r7/r8 - NO unroll pragmas on weight-load loops (breaks the
// compiler's load pipelining; VALUBusy 47->17%); r5/r6 - no >100-reg
// weight caching (spills at the backend's 4-waves/EU target).
// Numerics as verified rounds 2-8 (absmax 0.0234): fp64 matvec
// accumulation (order deltas ~1e-16 irrelevant), fp32 temp-50000
// softmax -> soft-argmax -> floor chain op-for-op like the reference.

#define CTX     256
#define INIT    32
#define HID     256
#define WIN     63
#define MSTEPS  224            // CTX - INIT
#define OUTROW  (MSTEPS + CTX) // 480
#define IT      4
#define NT      256

__global__ void __launch_bounds__(NT)
cpp_kernel(const float* __restrict__ x,
           const float* __restrict__ hid_W,
           const float* __restrict__ hid_b,
           const float* __restrict__ in_W,
           const float* __restrict__ in_b,
           const float* __restrict__ pred_W,
           const float* __restrict__ pred_b,
           float* __restrict__ out)
{
    __shared__ double s_x[IT][CTX];      // 8 KB fp64 x rows (broadcast reads)
    __shared__ double s_hid[IT][HID];    // 8 KB fp64 hidden carry
    __shared__ int    s_lastl[IT];
    __shared__ int    s_act[IT];

    const int tid  = threadIdx.x;
    const int lane = tid & 63;
    const int q    = tid >> 6;           // wave 0..3 == slot owner
    const int j    = tid;                // hidden unit (NT == HID)
    const int item0 = blockIdx.x * IT;

    const double bias  = (double)hid_b[j] + (double)in_b[j];
    const float  pbias = (lane < WIN) ? pred_b[lane] : 0.0f;

    // ---- init: wave q loads item q's x row, zeroes its out row, hid=1 ----
    {
        const int item = item0 + q;
        float* orow = out + (size_t)item * OUTROW;
        for (int idx = lane; idx < OUTROW; idx += 64) orow[idx] = 0.0f;
        #pragma unroll
        for (int u = 0; u < 4; ++u)
            s_x[q][lane + 64 * u] = (double)x[(size_t)item * CTX + lane + 64 * u];
        #pragma unroll
        for (int u = 0; u < 4; ++u) s_hid[q][lane + 64 * u] = 1.0;
        if (lane == 0) { s_lastl[q] = INIT; s_act[q] = 1; }
    }

    // wave-local slot state (wave q owns item q; uniform across the wave)
    float mylast = (float)INIT;
    int   sc = 0;
    __syncthreads();

    for (int iter = 0; iter < MSTEPS; ++iter) {
        int lastl[IT], act[IT];
        #pragma unroll
        for (int it = 0; it < IT; ++it) { lastl[it] = s_lastl[it]; act[it] = s_act[it]; }
        if (!(act[0] | act[1] | act[2] | act[3])) break;

        // ---- Phase A: full 288-dot pre-activation for unit j, all 4 items ----
        double acc[IT];
        #pragma unroll
        for (int it = 0; it < IT; ++it) acc[it] = bias;

        {
            int sb[IT];
            #pragma unroll
            for (int it = 0; it < IT; ++it) {
                int l = lastl[it]; if (l > CTX) l = CTX;
                sb[it] = l - INIT;                    // in [0, 224]
            }
            #pragma unroll 4
            for (int m = 0; m < INIT; ++m) {
                const double wv = (double)in_W[m * HID + j];
                #pragma unroll
                for (int it = 0; it < IT; ++it)
                    acc[it] = fma(s_x[it][sb[it] + m], wv, acc[it]);
            }
        }
        for (int k = 0; k < HID; k += 4) {            // r4's proven loop form
            const double w0 = (double)hid_W[(size_t)(k + 0) * HID + j];
            const double w1 = (double)hid_W[(size_t)(k + 1) * HID + j];
            const double w2 = (double)hid_W[(size_t)(k + 2) * HID + j];
            const double w3 = (double)hid_W[(size_t)(k + 3) * HID + j];
            #pragma unroll
            for (int it = 0; it < IT; ++it) {
                const double2 hA = *(const double2*)&s_hid[it][k];
                const double2 hB = *(const double2*)&s_hid[it][k + 2];
                acc[it] = fma(hA.x, w0, acc[it]);
                acc[it] = fma(hA.y, w1, acc[it]);
                acc[it] = fma(hB.x, w2, acc[it]);
                acc[it] = fma(hB.y, w3, acc[it]);
            }
        }
        __syncthreads();   // (1) all old-s_hid reads done

        #pragma unroll
        for (int it = 0; it < IT; ++it)
            if (act[it]) s_hid[it][j] = (double)tanhf((float)acc[it]);
        __syncthreads();   // (2) new hidden visible

        // ---- Phase B+C: wave q owns item q: direct w[lane], softmax, scatter ----
        if (act[q]) {
            const int it = q;
            float t = -INFINITY;
            if (lane < WIN) {
                double wacc = 0.0;
                for (int k = 0; k < HID; k += 4) {
                    const double p0 = (double)pred_W[(k + 0) * WIN + lane];
                    const double p1 = (double)pred_W[(k + 1) * WIN + lane];
                    const double p2 = (double)pred_W[(k + 2) * WIN + lane];
                    const double p3 = (double)pred_W[(k + 3) * WIN + lane];
                    const double2 hA = *(const double2*)&s_hid[it][k];
                    const double2 hB = *(const double2*)&s_hid[it][k + 2];
                    wacc = fma(hA.x, p0, wacc);
                    wacc = fma(hA.y, p1, wacc);
                    wacc = fma(hB.x, p2, wacc);
                    wacc = fma(hB.y, p3, wacc);
                }
                const double wv = wacc + (double)pbias;
                t = (float)wv * 50000.0f;            // fp32 temp scale like ref
            }
            float mx = t;
            #pragma unroll
            for (int off = 32; off > 0; off >>= 1)
                mx = fmaxf(mx, __shfl_xor(mx, off));
            const float e = (lane < WIN) ? expf(t - mx) : 0.0f;
            float S = e;
            #pragma unroll
            for (int off = 32; off > 0; off >>= 1)
                S += __shfl_xor(S, off);
            const float p = e / S;
            float D = p * (float)lane;
            #pragma unroll
            for (int off = 32; off > 0; off >>= 1)
                D += __shfl_xor(D, off);
            float cur = fminf(D + 1.0f, 63.0f);
            float se = fminf(cur + mylast, 256.0f);
            const int sel = (int)se;

            float* orow = out + (size_t)(item0 + it) * OUTROW;
            if (lane < WIN) {
                const int pos = lastl[it] + lane;
                if (pos < sel) {
                    const float msk = 1.0f / (1.0f + expf((float)lane - cur));
                    orow[MSTEPS + pos] = msk * (float)s_x[it][pos];
                }
            }
            const bool done = (se >= 256.0f);        // final step's pt is dropped
            if (lane == 0) {
                if (!done) { orow[sc] = se; s_lastl[it] = sel; }
                else       { s_act[it] = 0; }
            }
            sc++;
            mylast = se;
        }
        __syncthreads();   // (3) state updates visible for next Phase A
    }
}

extern "C" void kernel_launch(void* const* d_in, const int* in_sizes, int n_in,
                              void* d_out, int out_size, void* d_ws, size_t ws_size,
                              hipStream_t stream) {
    const float* x      = (const float*)d_in[0];
    const float* hid_W  = (const float*)d_in[1];
    const float* hid_b  = (const float*)d_in[2];
    const float* in_W   = (const float*)d_in[3];
    const float* in_b   = (const float*)d_in[4];
    const float* pred_W = (const float*)d_in[5];
    const float* pred_b = (const float*)d_in[6];
    float* out = (float*)d_out;

    const int B = in_sizes[0] / CTX;     // 4096
    const int nblocks = B / IT;          // 1024
    cpp_kernel<<<nblocks, NT, 0, stream>>>(x, hid_W, hid_b, in_W, in_b,
                                           pred_W, pred_b, out);
}